// Round 7
// baseline (131.504 us; speedup 1.0000x reference)
//
#include <hip/hip_runtime.h>
#include <cstdint>
#include <cstddef>

// EcoAttention: block-local top-p truncated attention, S=4096 D=128 BLOCK=64.
//
// R7: wave-private post-QK pipeline.
//  - 16x16x32 QK: each wave owns 16 complete score rows -> scores/sort/
//    weights/PV live in per-wave LDS scratch, NO workgroup barrier between
//    them (wave-lockstep + wave_barrier for compiler ordering).
//  - 2 barriers/iter: B1 "staging done" / B0 "QK reads done"; K image for
//    j+1 prefetched via global_load_lds right after B0, overlapping sort+PV.
//  - Vt no longer in LDS: prep emits Vt in PV B-frag linear order; PV reads
//    it straight from global (L2-resident, coalesced 16B/lane).
//  - LDS 48KB K-planes + 17KB scratch = 66.5KB -> 2 WG/CU.

#define SEQ   4096
#define DIM   128
#define BLK   64
#define NB    (SEQ / BLK)   // 64
#define NJG   8             // j-groups (512 WGs)
#define JPB   (NB / NJG)    // 8 key blocks per WG
#define NT    256
#define SSTR  68            // private score row stride (fp32)
#define WSCR  1088          // floats per wave scratch (16*68)
#define THRESH 0.95f
#define EPSF   1e-8f

typedef __attribute__((ext_vector_type(8))) short bf16x8;
typedef __attribute__((ext_vector_type(4))) float f32x4;

#define MFMA16(a, b, c) __builtin_amdgcn_mfma_f32_16x16x32_bf16((a), (b), (c), 0, 0, 0)

union U4 { uint4 u; bf16x8 v; };

__device__ __forceinline__ uint bf16_rtn_bits(float x) {
  uint u = __float_as_uint(x);
  return (u + 0x7FFFu + ((u >> 16) & 1u)) & 0xFFFF0000u;
}

__device__ __forceinline__ void gll16(const uint* g, uint* l) {
  __builtin_amdgcn_global_load_lds(
      (const __attribute__((address_space(1))) void*)g,
      (__attribute__((address_space(3))) void*)l, 16, 0, 0);
}

// 3-way split of a 64x128 fp32 block into bf16 hi/mid/lo swizzled planes (LDS).
__device__ __forceinline__ void stage_split(const float* __restrict__ src,
                                            uint* __restrict__ sX, int tid) {
  const float4* g = (const float4*)src;
#pragma unroll
  for (int it = 0; it < 8; ++it) {
    int idx = it * NT + tid;
    int r = idx >> 5, c4 = idx & 31;
    float4 x = g[idx];
    float xs[4] = {x.x, x.y, x.z, x.w};
    uint h[4], m[4], l[4];
#pragma unroll
    for (int e = 0; e < 4; ++e) {
      float v  = xs[e];
      uint hb  = bf16_rtn_bits(v);
      float r1 = v - __uint_as_float(hb);
      uint mb  = __float_as_uint(r1) & 0xFFFF0000u;
      float r2 = r1 - __uint_as_float(mb);
      uint lb  = __float_as_uint(r2) & 0xFFFF0000u;
      h[e] = hb; m[e] = mb; l[e] = lb;
    }
    uint off = (uint)r * 64u + (((uint)(c4 >> 1) ^ (uint)(r & 15)) << 2) +
               (uint)((c4 & 1) << 1);
    *(uint2*)&sX[off]        = make_uint2((h[0] >> 16) | (h[1] & 0xFFFF0000u),
                                          (h[2] >> 16) | (h[3] & 0xFFFF0000u));
    *(uint2*)&sX[4096 + off] = make_uint2((m[0] >> 16) | (m[1] & 0xFFFF0000u),
                                          (m[2] >> 16) | (m[3] & 0xFFFF0000u));
    *(uint2*)&sX[8192 + off] = make_uint2((l[0] >> 16) | (l[1] & 0xFFFF0000u),
                                          (l[2] >> 16) | (l[3] & 0xFFFF0000u));
  }
}

// ---- prep: per key block, [Khi|Kmid|Klo (48KB) | Vt-frag (16KB)]; zero O ----
__global__ __launch_bounds__(NT, 2) void eco_prep_kernel(
    const float* __restrict__ K, const float* __restrict__ V,
    uint* __restrict__ P, float* __restrict__ O) {
  __shared__ __align__(16) uint sP[12288];
  const int tid = threadIdx.x;
  const int jb  = blockIdx.x;

  // zero the output (replaces a separate memset launch)
  {
    float4 z = {0.f, 0.f, 0.f, 0.f};
    float4* op = (float4*)O + (size_t)jb * (NT * 8);
#pragma unroll
    for (int it = 0; it < 8; ++it) op[it * NT + tid] = z;
  }

  // stage V fp32 -> padded tmp (stride 132) in sP
  {
    const float4* gv = (const float4*)(V + (size_t)jb * BLK * DIM);
    float* vt = (float*)sP;
#pragma unroll
    for (int it = 0; it < 8; ++it) {
      int idx = it * NT + tid;
      int r = idx >> 5, c4 = idx & 31;
      *(float4*)&vt[r * 132 + (c4 << 2)] = gv[idx];
    }
  }
  __syncthreads();
  // Vt in PV B-frag linear order: fragment idx = ch*128 + d (ch = c/8),
  // 8 bf16 = V[ch*8+j][d], written straight to global (coalesced).
  {
    const float* vt = (const float*)sP;
    uint4* dv = (uint4*)(P + (size_t)jb * 16384 + 12288);
#pragma unroll
    for (int f = 0; f < 4; ++f) {
      int idx = f * NT + tid;
      int ch = idx >> 7, d = idx & 127;
      uint b[8];
#pragma unroll
      for (int j = 0; j < 8; ++j)
        b[j] = bf16_rtn_bits(vt[(ch * 8 + j) * 132 + d]);
      dv[idx] = make_uint4((b[0] >> 16) | (b[1] & 0xFFFF0000u),
                           (b[2] >> 16) | (b[3] & 0xFFFF0000u),
                           (b[4] >> 16) | (b[5] & 0xFFFF0000u),
                           (b[6] >> 16) | (b[7] & 0xFFFF0000u));
    }
  }
  __syncthreads();  // V tmp dead
  stage_split(K + (size_t)jb * BLK * DIM, sP, tid);
  __syncthreads();
  {
    uint4* dst = (uint4*)(P + (size_t)jb * 16384);
    const uint4* p4 = (const uint4*)sP;
#pragma unroll
    for (int it = 0; it < 12; ++it) dst[it * NT + tid] = p4[it * NT + tid];
  }
}

// compile-time/lane-uniform-direction compare-exchange (desc if d)
#define CE(x, y, dmax) { float _hi = fmaxf((x), (y)); float _lo = fminf((x), (y)); \
                         (x) = (dmax) ? _hi : _lo; (y) = (dmax) ? _lo : _hi; }

__global__ __launch_bounds__(NT, 2) void eco_attn_kernel(
    const float* __restrict__ Q, const uint* __restrict__ P,
    float* __restrict__ O) {
  __shared__ __align__(16) uint sK[12288];   // 48 KB: Khi/Kmid/Klo planes
  __shared__ __align__(16) uint sScr[4352];  // 17 KB: 4 x 1088-float wave scratch

  const int tid  = threadIdx.x;
  const int ib   = blockIdx.y;
  const int jg   = blockIdx.x;
  const int lane = tid & 63;
  const int wv   = tid >> 6;
  const int quad = lane >> 4;   // 0..3
  const int l16  = lane & 15;

  float* sSw = (float*)sScr + wv * WSCR;  // this wave's score rows (16 x 68)
  uint*  sWw = sScr + wv * WSCR;          // weight overlay (16 x 32 uints)

  // ---- Q fragments (16x16x32 A): q-row = wv*16 + l16, k = ks*32+quad*8+j ----
  bf16x8 qh[4], qm[4], ql[4];
  {
    const float* qp = Q + (size_t)(ib * BLK + wv * 16 + l16) * DIM + quad * 8;
#pragma unroll
    for (int ks = 0; ks < 4; ++ks) {
      float4 x0 = *(const float4*)(qp + ks * 32);
      float4 x1 = *(const float4*)(qp + ks * 32 + 4);
      float xs[8] = {x0.x, x0.y, x0.z, x0.w, x1.x, x1.y, x1.z, x1.w};
      uint hb[8], mb[8], lb[8];
#pragma unroll
      for (int e = 0; e < 8; ++e) {
        float v  = xs[e];
        uint h   = bf16_rtn_bits(v);
        float r1 = v - __uint_as_float(h);
        uint m   = __float_as_uint(r1) & 0xFFFF0000u;
        float r2 = r1 - __uint_as_float(m);
        uint l   = __float_as_uint(r2) & 0xFFFF0000u;
        hb[e] = h; mb[e] = m; lb[e] = l;
      }
      U4 uh, um, ul;
      uh.u = make_uint4((hb[0] >> 16) | (hb[1] & 0xFFFF0000u),
                        (hb[2] >> 16) | (hb[3] & 0xFFFF0000u),
                        (hb[4] >> 16) | (hb[5] & 0xFFFF0000u),
                        (hb[6] >> 16) | (hb[7] & 0xFFFF0000u));
      um.u = make_uint4((mb[0] >> 16) | (mb[1] & 0xFFFF0000u),
                        (mb[2] >> 16) | (mb[3] & 0xFFFF0000u),
                        (mb[4] >> 16) | (mb[5] & 0xFFFF0000u),
                        (mb[6] >> 16) | (mb[7] & 0xFFFF0000u));
      ul.u = make_uint4((lb[0] >> 16) | (lb[1] & 0xFFFF0000u),
                        (lb[2] >> 16) | (lb[3] & 0xFFFF0000u),
                        (lb[4] >> 16) | (lb[5] & 0xFFFF0000u),
                        (lb[6] >> 16) | (lb[7] & 0xFFFF0000u));
      qh[ks] = uh.v; qm[ks] = um.v; ql[ks] = ul.v;
    }
  }

  const f32x4 zf = {0.f, 0.f, 0.f, 0.f};
  f32x4 pv[8];
#pragma unroll
  for (int i = 0; i < 8; ++i) pv[i] = zf;

  // prologue: stage first K image
  {
    const uint* gsrc = P + (size_t)(jg * JPB) * 16384;
#pragma unroll
    for (int it = 0; it < 12; ++it) {
      int idx = (it * NT + tid) << 2;
      gll16(gsrc + idx, sK + idx);
    }
  }

  for (int jj = 0; jj < JPB; ++jj) {
    const int jb = jg * JPB + jj;
    __syncthreads();  // B1: K image staged (drains this wave's vmcnt + barrier)

    // ---- QK^T: 4 n-tiles x 4 ks x 8 split terms = 128 MFMA16 ----
    f32x4 ahh[4], al1[4], al2[4];
#pragma unroll
    for (int nt = 0; nt < 4; ++nt) { ahh[nt] = zf; al1[nt] = zf; al2[nt] = zf; }
#pragma unroll
    for (int nt = 0; nt < 4; ++nt) {
      const int rB = nt * 16 + l16;
      const uint rowoff = (uint)rB * 64u;
      const uint swk = (uint)(rB & 15);
#pragma unroll
      for (int ks = 0; ks < 4; ++ks) {
        uint off = rowoff + ((((uint)(ks * 4 + quad)) ^ swk) << 2);
        bf16x8 bh = *(const bf16x8*)&sK[off];
        bf16x8 bm = *(const bf16x8*)&sK[4096 + off];
        bf16x8 bl = *(const bf16x8*)&sK[8192 + off];
        ahh[nt] = MFMA16(qh[ks], bh, ahh[nt]);
        al1[nt] = MFMA16(qh[ks], bm, al1[nt]);
        al2[nt] = MFMA16(qm[ks], bh, al2[nt]);
        al1[nt] = MFMA16(qh[ks], bl, al1[nt]);
        al2[nt] = MFMA16(ql[ks], bh, al2[nt]);
        al1[nt] = MFMA16(qm[ks], bm, al1[nt]);
        al2[nt] = MFMA16(qm[ks], bl, al2[nt]);
        al1[nt] = MFMA16(ql[ks], bm, al1[nt]);
      }
    }
    __syncthreads();  // B0: all waves done reading sK

    // ---- prefetch next K image (overlaps sort + PV below) ----
    if (jj + 1 < JPB) {
      const uint* gsrc = P + (size_t)(jb + 1) * 16384;
#pragma unroll
      for (int it = 0; it < 12; ++it) {
        int idx = (it * NT + tid) << 2;
        gll16(gsrc + idx, sK + idx);
      }
    }

    // ---- scores -> wave-private scratch (C-layout: row=quad*4+rg, col=nt*16+l16)
#pragma unroll
    for (int nt = 0; nt < 4; ++nt) {
      f32x4 s = ahh[nt] + (al1[nt] + al2[nt]);
#pragma unroll
      for (int rg = 0; rg < 4; ++rg)
        sSw[(quad * 4 + rg) * SSTR + nt * 16 + l16] = s[rg];
    }
    __builtin_amdgcn_wave_barrier();  // pin order: score writes before sort reads

    // ---- top-p softmax: 4 lanes per row (row=l16, s=quad), 16 regs/lane ----
    {
      const int s = quad;
      const float* rowp = sSw + l16 * SSTR + s * 16;
      float a[16], e[16];
#pragma unroll
      for (int c = 0; c < 4; ++c) {
        float4 t4 = *(const float4*)(rowp + 4 * c);
        a[4 * c + 0] = t4.x; a[4 * c + 1] = t4.y;
        a[4 * c + 2] = t4.z; a[4 * c + 3] = t4.w;
      }
      float mt[8];
#pragma unroll
      for (int i = 0; i < 8; ++i) mt[i] = fmaxf(a[i], a[i + 8]);
#pragma unroll
      for (int w2 = 4; w2 >= 1; w2 >>= 1)
#pragma unroll
        for (int i = 0; i < w2; ++i) mt[i] = fmaxf(mt[i], mt[i + w2]);
      float m = mt[0];
      m = fmaxf(m, __shfl_xor(m, 16, 64));
      m = fmaxf(m, __shfl_xor(m, 32, 64));
#pragma unroll
      for (int i = 0; i < 16; ++i) { a[i] = __expf(a[i] - m); e[i] = a[i]; }
      float st[8];
#pragma unroll
      for (int i = 0; i < 8; ++i) st[i] = a[i] + a[i + 8];
#pragma unroll
      for (int w2 = 4; w2 >= 1; w2 >>= 1)
#pragma unroll
        for (int i = 0; i < w2; ++i) st[i] += st[i + w2];
      float sr = st[0];
      sr += __shfl_xor(sr, 16, 64);
      sr += __shfl_xor(sr, 32, 64);
      const float T = THRESH * sr;

      // bitonic sort DESC over 64 = 4 lanes x 16 regs
#pragma unroll
      for (int k2 = 2; k2 <= 8; k2 <<= 1)
#pragma unroll
        for (int j2 = k2 >> 1; j2 >= 1; j2 >>= 1)
#pragma unroll
          for (int i = 0; i < 16; ++i) {
            int l = i ^ j2;
            if (l > i) { bool d = ((i & k2) == 0); CE(a[i], a[l], d); }
          }
      const bool x16 = ((s & 1) == 0);
      const bool x32 = ((s & 2) == 0);
#pragma unroll
      for (int j2 = 8; j2 >= 1; j2 >>= 1)
#pragma unroll
        for (int i = 0; i < 16; ++i) {
          int l = i ^ j2;
          if (l > i) { CE(a[i], a[l], x16); }
        }
      {
        const bool km = (x32 == x16);
#pragma unroll
        for (int i = 0; i < 16; ++i) {
          float o = __shfl_xor(a[i], 16, 64);
          a[i] = km ? fmaxf(a[i], o) : fminf(a[i], o);
        }
#pragma unroll
        for (int j2 = 8; j2 >= 1; j2 >>= 1)
#pragma unroll
          for (int i = 0; i < 16; ++i) {
            int l = i ^ j2;
            if (l > i) { CE(a[i], a[l], x32); }
          }
      }
      {
#pragma unroll
        for (int i = 0; i < 16; ++i) {
          float o = __shfl_xor(a[i], 32, 64);
          a[i] = x32 ? fmaxf(a[i], o) : fminf(a[i], o);
        }
#pragma unroll
        for (int i = 0; i < 16; ++i) {
          float o = __shfl_xor(a[i], 16, 64);
          a[i] = x16 ? fmaxf(a[i], o) : fminf(a[i], o);
        }
#pragma unroll
        for (int j2 = 8; j2 >= 1; j2 >>= 1)
#pragma unroll
          for (int i = 0; i < 16; ++i) {
            int l = i ^ j2;
            if (l > i) { CE(a[i], a[l], true); }
          }
      }
      // global inclusive cumsum, count t, renormalize first-t (orig order)
#pragma unroll
      for (int i = 1; i < 16; ++i) a[i] += a[i - 1];
      float tot = a[15];
      float c = tot;
      float o1 = __shfl_up(c, 16, 64); if (s >= 1) c += o1;
      float o2 = __shfl_up(c, 32, 64); if (s >= 2) c += o2;
      const float excl = c - tot;
      int cnt = 0;
#pragma unroll
      for (int i = 0; i < 16; ++i) cnt += ((a[i] + excl) < T) ? 1 : 0;
      cnt += __shfl_xor(cnt, 16, 64);
      cnt += __shfl_xor(cnt, 32, 64);
      const int t = cnt;
      const int base = s * 16;
      float p = 0.f;
#pragma unroll
      for (int i = 0; i < 16; ++i) p += (base + i < t) ? e[i] : 0.f;
      p += __shfl_xor(p, 16, 64);
      p += __shfl_xor(p, 32, 64);
      const float rn = 1.0f / (p + EPSF);
      // emit bf16 weights in PV A-frag layout (row = l16, chunks 2s, 2s+1)
      uint* wrow = sWw + l16 * 32;
#pragma unroll
      for (int b = 0; b < 2; ++b) {
        uint pk[4];
#pragma unroll
        for (int ii = 0; ii < 4; ++ii) {
          int i0 = b * 8 + ii * 2;
          float w0 = (base + i0     < t) ? e[i0]     * rn : 0.f;
          float w1 = (base + i0 + 1 < t) ? e[i0 + 1] * rn : 0.f;
          pk[ii] = (bf16_rtn_bits(w0) >> 16) | (bf16_rtn_bits(w1) & 0xFFFF0000u);
        }
        *(uint4*)&wrow[((uint)(2 * s + b) ^ (uint)(l16 & 7)) << 2] =
            make_uint4(pk[0], pk[1], pk[2], pk[3]);
      }
    }
    __builtin_amdgcn_wave_barrier();  // pin order: weight writes before PV reads

    // ---- PV: A = bf16 weights (private), B = Vt-frag from global (L2) ----
    bf16x8 wf[2];
#pragma unroll
    for (int ks2 = 0; ks2 < 2; ++ks2)
      wf[ks2] = *(const bf16x8*)&sWw[(uint)l16 * 32u +
                 ((((uint)(ks2 * 4 + quad)) ^ (uint)(l16 & 7)) << 2)];
    {
      const uint* gvt = P + (size_t)jb * 16384 + 12288;
#pragma unroll
      for (int nt2 = 0; nt2 < 8; ++nt2) {
#pragma unroll
        for (int ks2 = 0; ks2 < 2; ++ks2) {
          bf16x8 vf = *(const bf16x8*)&gvt[((uint)((ks2 * 4 + quad) * 128 +
                                                   nt2 * 16 + l16)) << 2];
          pv[nt2] = MFMA16(wf[ks2], vf, pv[nt2]);
        }
      }
    }
  }

  // ---- epilogue: C-layout -> global atomicAdd over the 8 j-groups ----
#pragma unroll
  for (int nt2 = 0; nt2 < 8; ++nt2) {
    const int col  = nt2 * 16 + l16;
    const int row0 = ib * BLK + wv * 16 + quad * 4;
#pragma unroll
    for (int rg = 0; rg < 4; ++rg)
      atomicAdd(O + (size_t)(row0 + rg) * DIM + col, pv[nt2][rg]);
  }
}

extern "C" void kernel_launch(void* const* d_in, const int* in_sizes, int n_in,
                              void* d_out, int out_size, void* d_ws, size_t ws_size,
                              hipStream_t stream) {
  (void)in_sizes; (void)n_in; (void)ws_size; (void)out_size;
  const float* q = (const float*)d_in[0];
  const float* k = (const float*)d_in[1];
  const float* v = (const float*)d_in[2];
  float* out = (float*)d_out;
  uint* prep = (uint*)d_ws;   // 64 blocks x 64 KB = 4 MB

  eco_prep_kernel<<<dim3(NB), dim3(NT), 0, stream>>>(k, v, prep, out);
  eco_attn_kernel<<<dim3(NJG, NB), dim3(NT), 0, stream>>>(q, prep, out);
}

// Round 8
// 123.093 us; speedup vs baseline: 1.0683x; 1.0683x over previous
//
#include <hip/hip_runtime.h>
#include <cstdint>
#include <cstddef>

// EcoAttention: block-local top-p truncated attention, S=4096 D=128 BLOCK=64.
//
// R8: f16 2-term split replaces bf16 3-term split (f16 11-bit significand:
//     residual 2^-22 -> same score accuracy, 3 MFMA terms instead of 8,
//     2 K planes instead of 3). LDS 49KB -> 3 WG/CU (12 waves/CU) with
//     __launch_bounds__(256,3); NJG=16 (1024 WGs) to fill the capacity.
//     PV + weights in f16 (output error ~8x lower than bf16).
//     Wave-private post-QK pipeline and K-prefetch retained from R7.

#define SEQ   4096
#define DIM   128
#define BLK   64
#define NB    (SEQ / BLK)   // 64
#define NJG   16            // j-groups (1024 WGs)
#define JPB   (NB / NJG)    // 4 key blocks per WG
#define NT    256
#define PSTR  12288         // uints per prepped block (Khi 16KB | Kr 16KB | Vt 16KB)
#define SSTR  68            // private score row stride (fp32)
#define WSCR  1088          // floats per wave scratch (16*68)
#define THRESH 0.95f
#define EPSF   1e-8f

typedef __attribute__((ext_vector_type(8))) _Float16 f16x8;
typedef __attribute__((ext_vector_type(4))) float    f32x4;

#define MFMAH(a, b, c) __builtin_amdgcn_mfma_f32_16x16x32_f16((a), (b), (c), 0, 0, 0)

union UH4 { uint2 u; _Float16 h[4]; };
union UH8 { uint4 u; f16x8 v; };

__device__ __forceinline__ void gll16(const uint* g, uint* l) {
  __builtin_amdgcn_global_load_lds(
      (const __attribute__((address_space(1))) void*)g,
      (__attribute__((address_space(3))) void*)l, 16, 0, 0);
}

// 2-term f16 split of a 64x128 fp32 block into hi/res swizzled planes (LDS).
// Element (r, c): chunk = c/8, uint offset r*64 + ((chunk ^ (r&15))*4) + (c%8)/2.
__device__ __forceinline__ void stage_split_f16(const float* __restrict__ src,
                                                uint* __restrict__ sX, int tid) {
  const float4* g = (const float4*)src;
#pragma unroll
  for (int it = 0; it < 8; ++it) {
    int idx = it * NT + tid;
    int r = idx >> 5, c4 = idx & 31;   // 4 floats at cols c4*4..+3
    float4 x = g[idx];
    float xs[4] = {x.x, x.y, x.z, x.w};
    UH4 uh, ur;
#pragma unroll
    for (int e = 0; e < 4; ++e) {
      float v = xs[e];
      _Float16 h = (_Float16)v;
      float r1 = v - (float)h;          // exact (Sterbenz)
      uh.h[e] = h;
      ur.h[e] = (_Float16)r1;
    }
    uint off = (uint)r * 64u + (((uint)(c4 >> 1) ^ (uint)(r & 15)) << 2) +
               (uint)((c4 & 1) << 1);
    *(uint2*)&sX[off]        = uh.u;
    *(uint2*)&sX[4096 + off] = ur.u;
  }
}

// ---- prep: per key block build [Khi|Kr|Vt-frag] 48KB image; zero O ----
__global__ __launch_bounds__(NT, 2) void eco_prep_kernel(
    const float* __restrict__ K, const float* __restrict__ V,
    uint* __restrict__ P, float* __restrict__ O) {
  __shared__ __align__(16) uint sP[12288];   // 48 KB (V fp32 bounce, then K planes)
  const int tid = threadIdx.x;
  const int jb  = blockIdx.x;

  // zero the output (replaces a separate memset launch)
  {
    float4 z = {0.f, 0.f, 0.f, 0.f};
    float4* op = (float4*)O + (size_t)jb * (NT * 8);
#pragma unroll
    for (int it = 0; it < 8; ++it) op[it * NT + tid] = z;
  }

  // stage V fp32 -> padded tmp (stride 132) in sP
  {
    const float4* gv = (const float4*)(V + (size_t)jb * BLK * DIM);
    float* vt = (float*)sP;
#pragma unroll
    for (int it = 0; it < 8; ++it) {
      int idx = it * NT + tid;
      int r = idx >> 5, c4 = idx & 31;
      *(float4*)&vt[r * 132 + (c4 << 2)] = gv[idx];
    }
  }
  __syncthreads();
  // Vt in PV B-frag linear order: frag idx = ch*128 + d (ch = c/8),
  // 8 f16 = V[ch*8+j][d], written straight to global (coalesced).
  {
    const float* vt = (const float*)sP;
    uint4* dv = (uint4*)(P + (size_t)jb * PSTR + 8192);
#pragma unroll
    for (int f = 0; f < 4; ++f) {
      int idx = f * NT + tid;
      int ch = idx >> 7, d = idx & 127;
      UH8 u;
#pragma unroll
      for (int j = 0; j < 8; ++j)
        u.v[j] = (_Float16)vt[(ch * 8 + j) * 132 + d];
      dv[idx] = u.u;
    }
  }
  __syncthreads();  // V tmp dead
  stage_split_f16(K + (size_t)jb * BLK * DIM, sP, tid);
  __syncthreads();
  {
    uint4* dst = (uint4*)(P + (size_t)jb * PSTR);
    const uint4* p4 = (const uint4*)sP;
#pragma unroll
    for (int it = 0; it < 8; ++it) dst[it * NT + tid] = p4[it * NT + tid];
  }
}

// lane-uniform-direction compare-exchange (desc if d)
#define CE(x, y, dmax) { float _hi = fmaxf((x), (y)); float _lo = fminf((x), (y)); \
                         (x) = (dmax) ? _hi : _lo; (y) = (dmax) ? _lo : _hi; }

__global__ __launch_bounds__(NT, 3) void eco_attn_kernel(
    const float* __restrict__ Q, const uint* __restrict__ P,
    float* __restrict__ O) {
  __shared__ __align__(16) uint sK[8192];    // 32 KB: Khi / Kr planes
  __shared__ __align__(16) uint sScr[4352];  // 17 KB: 4 x 1088-float wave scratch

  const int tid  = threadIdx.x;
  const int ib   = blockIdx.y;
  const int jg   = blockIdx.x;
  const int lane = tid & 63;
  const int wv   = tid >> 6;
  const int quad = lane >> 4;   // 0..3
  const int l16  = lane & 15;

  float* sSw = (float*)sScr + wv * WSCR;  // this wave's score rows (16 x 68)
  uint*  sWw = sScr + wv * WSCR;          // weight overlay (16 rows x 32 uints)

  // ---- Q fragments (16x16x32 A): q-row = wv*16+l16, k = ks*32+quad*8+j ----
  f16x8 qh[4], qr[4];
  {
    const float* qp = Q + (size_t)(ib * BLK + wv * 16 + l16) * DIM + quad * 8;
#pragma unroll
    for (int ks = 0; ks < 4; ++ks) {
      float4 x0 = *(const float4*)(qp + ks * 32);
      float4 x1 = *(const float4*)(qp + ks * 32 + 4);
      float xs[8] = {x0.x, x0.y, x0.z, x0.w, x1.x, x1.y, x1.z, x1.w};
      f16x8 h8, r8;
#pragma unroll
      for (int e = 0; e < 8; ++e) {
        float v = xs[e];
        _Float16 h = (_Float16)v;
        float r1 = v - (float)h;
        h8[e] = h;
        r8[e] = (_Float16)r1;
      }
      qh[ks] = h8; qr[ks] = r8;
    }
  }

  const f32x4 zf = {0.f, 0.f, 0.f, 0.f};
  f32x4 pv[8];
#pragma unroll
  for (int i = 0; i < 8; ++i) pv[i] = zf;

  // prologue: stage first K image (32KB = 8 x 16B per thread)
  {
    const uint* gsrc = P + (size_t)(jg * JPB) * PSTR;
#pragma unroll
    for (int it = 0; it < 8; ++it) {
      int idx = (it * NT + tid) << 2;
      gll16(gsrc + idx, sK + idx);
    }
  }

  for (int jj = 0; jj < JPB; ++jj) {
    const int jb = jg * JPB + jj;
    __syncthreads();  // B1: K image staged (drains vmcnt + barrier)

    // ---- QK^T: 4 n-tiles x 4 ks x 3 split terms = 48 MFMA ----
    f32x4 ah[4], ar[4];
#pragma unroll
    for (int nt = 0; nt < 4; ++nt) { ah[nt] = zf; ar[nt] = zf; }
#pragma unroll
    for (int nt = 0; nt < 4; ++nt) {
      const int rB = nt * 16 + l16;
      const uint rowoff = (uint)rB * 64u;
      const uint swk = (uint)(rB & 15);
#pragma unroll
      for (int ks = 0; ks < 4; ++ks) {
        uint off = rowoff + ((((uint)(ks * 4 + quad)) ^ swk) << 2);
        f16x8 bh = *(const f16x8*)&sK[off];
        f16x8 br = *(const f16x8*)&sK[4096 + off];
        ah[nt] = MFMAH(qh[ks], bh, ah[nt]);
        ar[nt] = MFMAH(qh[ks], br, ar[nt]);
        ar[nt] = MFMAH(qr[ks], bh, ar[nt]);
      }
    }
    __syncthreads();  // B0: all waves done reading sK

    // ---- prefetch next K image (overlaps sort + PV below) ----
    if (jj + 1 < JPB) {
      const uint* gsrc = P + (size_t)(jb + 1) * PSTR;
#pragma unroll
      for (int it = 0; it < 8; ++it) {
        int idx = (it * NT + tid) << 2;
        gll16(gsrc + idx, sK + idx);
      }
    }

    // ---- scores -> wave-private scratch (C-layout: row=quad*4+rg, col=nt*16+l16)
#pragma unroll
    for (int nt = 0; nt < 4; ++nt) {
      f32x4 s = ah[nt] + ar[nt];
#pragma unroll
      for (int rg = 0; rg < 4; ++rg)
        sSw[(quad * 4 + rg) * SSTR + nt * 16 + l16] = s[rg];
    }
    __builtin_amdgcn_wave_barrier();  // score writes before sort reads

    // ---- top-p softmax: 4 lanes per row (row=l16, s=quad), 16 regs/lane ----
    {
      const int s = quad;
      const float* rowp = sSw + l16 * SSTR + s * 16;
      float a[16], e[16];
#pragma unroll
      for (int c = 0; c < 4; ++c) {
        float4 t4 = *(const float4*)(rowp + 4 * c);
        a[4 * c + 0] = t4.x; a[4 * c + 1] = t4.y;
        a[4 * c + 2] = t4.z; a[4 * c + 3] = t4.w;
      }
      float mt[8];
#pragma unroll
      for (int i = 0; i < 8; ++i) mt[i] = fmaxf(a[i], a[i + 8]);
#pragma unroll
      for (int w2 = 4; w2 >= 1; w2 >>= 1)
#pragma unroll
        for (int i = 0; i < w2; ++i) mt[i] = fmaxf(mt[i], mt[i + w2]);
      float m = mt[0];
      m = fmaxf(m, __shfl_xor(m, 16, 64));
      m = fmaxf(m, __shfl_xor(m, 32, 64));
#pragma unroll
      for (int i = 0; i < 16; ++i) { a[i] = __expf(a[i] - m); e[i] = a[i]; }
      float st[8];
#pragma unroll
      for (int i = 0; i < 8; ++i) st[i] = a[i] + a[i + 8];
#pragma unroll
      for (int w2 = 4; w2 >= 1; w2 >>= 1)
#pragma unroll
        for (int i = 0; i < w2; ++i) st[i] += st[i + w2];
      float sr = st[0];
      sr += __shfl_xor(sr, 16, 64);
      sr += __shfl_xor(sr, 32, 64);
      const float T = THRESH * sr;

      // bitonic sort DESC over 64 = 4 lanes x 16 regs
#pragma unroll
      for (int k2 = 2; k2 <= 8; k2 <<= 1)
#pragma unroll
        for (int j2 = k2 >> 1; j2 >= 1; j2 >>= 1)
#pragma unroll
          for (int i = 0; i < 16; ++i) {
            int l = i ^ j2;
            if (l > i) { bool d = ((i & k2) == 0); CE(a[i], a[l], d); }
          }
      const bool x16 = ((s & 1) == 0);
      const bool x32 = ((s & 2) == 0);
#pragma unroll
      for (int j2 = 8; j2 >= 1; j2 >>= 1)
#pragma unroll
        for (int i = 0; i < 16; ++i) {
          int l = i ^ j2;
          if (l > i) { CE(a[i], a[l], x16); }
        }
      {
        const bool km = (x32 == x16);
#pragma unroll
        for (int i = 0; i < 16; ++i) {
          float o = __shfl_xor(a[i], 16, 64);
          a[i] = km ? fmaxf(a[i], o) : fminf(a[i], o);
        }
#pragma unroll
        for (int j2 = 8; j2 >= 1; j2 >>= 1)
#pragma unroll
          for (int i = 0; i < 16; ++i) {
            int l = i ^ j2;
            if (l > i) { CE(a[i], a[l], x32); }
          }
      }
      {
#pragma unroll
        for (int i = 0; i < 16; ++i) {
          float o = __shfl_xor(a[i], 32, 64);
          a[i] = x32 ? fmaxf(a[i], o) : fminf(a[i], o);
        }
#pragma unroll
        for (int i = 0; i < 16; ++i) {
          float o = __shfl_xor(a[i], 16, 64);
          a[i] = x16 ? fmaxf(a[i], o) : fminf(a[i], o);
        }
#pragma unroll
        for (int j2 = 8; j2 >= 1; j2 >>= 1)
#pragma unroll
          for (int i = 0; i < 16; ++i) {
            int l = i ^ j2;
            if (l > i) { CE(a[i], a[l], true); }
          }
      }
      // global inclusive cumsum, count t, renormalize first-t (orig order)
#pragma unroll
      for (int i = 1; i < 16; ++i) a[i] += a[i - 1];
      float tot = a[15];
      float c = tot;
      float o1 = __shfl_up(c, 16, 64); if (s >= 1) c += o1;
      float o2 = __shfl_up(c, 32, 64); if (s >= 2) c += o2;
      const float excl = c - tot;
      int cnt = 0;
#pragma unroll
      for (int i = 0; i < 16; ++i) cnt += ((a[i] + excl) < T) ? 1 : 0;
      cnt += __shfl_xor(cnt, 16, 64);
      cnt += __shfl_xor(cnt, 32, 64);
      const int t = cnt;
      const int base = s * 16;
      float p = 0.f;
#pragma unroll
      for (int i = 0; i < 16; ++i) p += (base + i < t) ? e[i] : 0.f;
      p += __shfl_xor(p, 16, 64);
      p += __shfl_xor(p, 32, 64);
      const float rn = 1.0f / (p + EPSF);
      // emit f16 weights in PV A-frag layout (row = l16, chunks 2s, 2s+1)
      uint* wrow = sWw + l16 * 32;
#pragma unroll
      for (int b = 0; b < 2; ++b) {
        f16x8 w8;
#pragma unroll
        for (int ii = 0; ii < 8; ++ii) {
          int i0 = b * 8 + ii;
          float w = (base + i0 < t) ? e[i0] * rn : 0.f;
          w8[ii] = (_Float16)w;
        }
        *(f16x8*)&wrow[((uint)(2 * s + b) ^ (uint)(l16 & 7)) << 2] = w8;
      }
    }
    __builtin_amdgcn_wave_barrier();  // weight writes before PV reads

    // ---- PV: A = f16 weights (private), B = Vt-frag from global (L2) ----
    f16x8 wf[2];
#pragma unroll
    for (int ks2 = 0; ks2 < 2; ++ks2)
      wf[ks2] = *(const f16x8*)&sWw[(uint)l16 * 32u +
                 ((((uint)(ks2 * 4 + quad)) ^ (uint)(l16 & 7)) << 2)];
    {
      const uint* gvt = P + (size_t)jb * PSTR + 8192;
#pragma unroll
      for (int nt2 = 0; nt2 < 8; ++nt2) {
#pragma unroll
        for (int ks2 = 0; ks2 < 2; ++ks2) {
          f16x8 vf = *(const f16x8*)&gvt[((uint)((ks2 * 4 + quad) * 128 +
                                                 nt2 * 16 + l16)) << 2];
          pv[nt2] = MFMAH(wf[ks2], vf, pv[nt2]);
        }
      }
    }
  }

  // ---- epilogue: C-layout -> global atomicAdd over the 16 j-groups ----
#pragma unroll
  for (int nt2 = 0; nt2 < 8; ++nt2) {
    const int col  = nt2 * 16 + l16;
    const int row0 = ib * BLK + wv * 16 + quad * 4;
#pragma unroll
    for (int rg = 0; rg < 4; ++rg)
      atomicAdd(O + (size_t)(row0 + rg) * DIM + col, pv[nt2][rg]);
  }
}

extern "C" void kernel_launch(void* const* d_in, const int* in_sizes, int n_in,
                              void* d_out, int out_size, void* d_ws, size_t ws_size,
                              hipStream_t stream) {
  (void)in_sizes; (void)n_in; (void)ws_size; (void)out_size;
  const float* q = (const float*)d_in[0];
  const float* k = (const float*)d_in[1];
  const float* v = (const float*)d_in[2];
  float* out = (float*)d_out;
  uint* prep = (uint*)d_ws;   // 64 blocks x 48 KB = 3 MB

  eco_prep_kernel<<<dim3(NB), dim3(NT), 0, stream>>>(k, v, prep, out);
  eco_attn_kernel<<<dim3(NJG, NB), dim3(NT), 0, stream>>>(q, prep, out);
}

// Round 10
// 118.957 us; speedup vs baseline: 1.1055x; 1.0348x over previous
//
#include <hip/hip_runtime.h>
#include <cstdint>
#include <cstddef>

// EcoAttention: block-local top-p truncated attention, S=4096 D=128 BLOCK=64.
//
// R10 = R9 with the prep Vt OOB fixed (1024 fragments, idx = part*256+tid;
//       R9 iterated 2048 -> OOB read past V + corruption -> abort).
//  - MFMA(K,Q): C col(=lane&15) is the Q-row -> each lane holds 16 scores of
//    ONE Q-row (K idx = nt*16+quad*4+rg). Sort runs register-direct; the
//    score LDS round-trip and its barriers are gone.
//  - LDS = 32KB K-planes + 8KB weight scratch = 40KB -> 4 WG/CU; grid
//    1024 = exactly 4/CU, no tail; __launch_bounds__(256,4).
//  - prep: LDS-free, 256 WGs (coalesced K-split + Vt-frag emission +
//    distributed O zeroing).

#define SEQ   4096
#define DIM   128
#define BLK   64
#define NB    (SEQ / BLK)   // 64
#define NJG   16            // j-groups (1024 WGs)
#define JPB   (NB / NJG)    // 4 key blocks per WG
#define NT    256
#define PSTR  12288         // uints per prepped block (Khi 16KB | Kr 16KB | Vt 16KB)
#define THRESH 0.95f
#define EPSF   1e-8f

typedef __attribute__((ext_vector_type(8))) _Float16 f16x8;
typedef __attribute__((ext_vector_type(4))) float    f32x4;

#define MFMAH(a, b, c) __builtin_amdgcn_mfma_f32_16x16x32_f16((a), (b), (c), 0, 0, 0)

union UH4 { uint2 u; _Float16 h[4]; };
union UH8 { uint4 u; f16x8 v; };

__device__ __forceinline__ void gll16(const uint* g, uint* l) {
  __builtin_amdgcn_global_load_lds(
      (const __attribute__((address_space(1))) void*)g,
      (__attribute__((address_space(3))) void*)l, 16, 0, 0);
}

// ---- prep: LDS-free, 4 WGs per key block. Builds [Khi|Kr|Vt-frag] 48KB
//      images in d_ws and zeroes O. ----
__global__ __launch_bounds__(NT, 4) void eco_prep_kernel(
    const float* __restrict__ K, const float* __restrict__ V,
    uint* __restrict__ P, float* __restrict__ O) {
  const int tid  = threadIdx.x;
  const int b    = blockIdx.x;     // 0..255
  const int jb   = b >> 2;
  const int part = b & 3;

  // zero O slice (2MB spread over 256 WGs)
  {
    float4 z = {0.f, 0.f, 0.f, 0.f};
    float4* op = (float4*)O;
#pragma unroll
    for (int it = 0; it < 2; ++it) op[b * 512 + it * NT + tid] = z;
  }

  // K 2-term f16 split -> swizzled planes (element (r,c): chunk=c/8,
  // uint off r*64 + ((chunk ^ (r&15))*4) + (c%8)/2); 2048 float4 per block.
  {
    const float4* gk = (const float4*)(K + (size_t)jb * BLK * DIM);
    uint* dst = P + (size_t)jb * PSTR;
#pragma unroll
    for (int it = 0; it < 2; ++it) {
      int f = part * 512 + it * NT + tid;   // float4 idx 0..2047
      int r = f >> 5, c4 = f & 31;
      float4 x = gk[f];
      float xs[4] = {x.x, x.y, x.z, x.w};
      UH4 uh, ur;
#pragma unroll
      for (int e = 0; e < 4; ++e) {
        float v = xs[e];
        _Float16 h = (_Float16)v;
        uh.h[e] = h;
        ur.h[e] = (_Float16)(v - (float)h);   // exact residual (Sterbenz)
      }
      uint off = (uint)r * 64u + (((uint)(c4 >> 1) ^ (uint)(r & 15)) << 2) +
                 (uint)((c4 & 1) << 1);
      *(uint2*)&dst[off]        = uh.u;
      *(uint2*)&dst[4096 + off] = ur.u;
    }
  }

  // Vt in PV B-frag linear order: ONLY 1024 fragments (ch in [0,8), d in
  // [0,128)); frag idx = ch*128 + d, 8 f16 = V[ch*8+j][d]. One frag/thread.
  {
    const float* gv = V + (size_t)jb * BLK * DIM;
    uint4* dv = (uint4*)(P + (size_t)jb * PSTR + 8192);
    int idx = part * 256 + tid;            // frag idx 0..1023
    int ch = idx >> 7, d = idx & 127;
    UH8 u;
#pragma unroll
    for (int j = 0; j < 8; ++j)
      u.v[j] = (_Float16)gv[(ch * 8 + j) * DIM + d];
    dv[idx] = u.u;
  }
}

// lane-uniform-direction compare-exchange (desc if d)
#define CE(x, y, dmax) { float _hi = fmaxf((x), (y)); float _lo = fminf((x), (y)); \
                         (x) = (dmax) ? _hi : _lo; (y) = (dmax) ? _lo : _hi; }

__global__ __launch_bounds__(NT, 4) void eco_attn_kernel(
    const float* __restrict__ Q, const uint* __restrict__ P,
    float* __restrict__ O) {
  __shared__ __align__(16) uint sK[8192];   // 32 KB: Khi / Kr planes
  __shared__ __align__(16) uint sW[2048];   // 8 KB: 4 x (16 rows x 32 uints)

  const int tid  = threadIdx.x;
  const int ib   = blockIdx.y;
  const int jg   = blockIdx.x;
  const int lane = tid & 63;
  const int wv   = tid >> 6;
  const int quad = lane >> 4;   // 0..3
  const int l16  = lane & 15;
  const int q4   = quad << 2;

  uint* sWw = sW + wv * 512;    // this wave's weight rows (16 x 32 uints)

  // ---- Q fragments (B-operand now): q-row = wv*16+l16, k = ks*32+quad*8+j ----
  f16x8 qh[4], qr[4];
  {
    const float* qp = Q + (size_t)(ib * BLK + wv * 16 + l16) * DIM + quad * 8;
#pragma unroll
    for (int ks = 0; ks < 4; ++ks) {
      float4 x0 = *(const float4*)(qp + ks * 32);
      float4 x1 = *(const float4*)(qp + ks * 32 + 4);
      float xs[8] = {x0.x, x0.y, x0.z, x0.w, x1.x, x1.y, x1.z, x1.w};
      f16x8 h8, r8;
#pragma unroll
      for (int e = 0; e < 8; ++e) {
        float v = xs[e];
        _Float16 h = (_Float16)v;
        h8[e] = h;
        r8[e] = (_Float16)(v - (float)h);
      }
      qh[ks] = h8; qr[ks] = r8;
    }
  }

  const f32x4 zf = {0.f, 0.f, 0.f, 0.f};
  f32x4 pv[8];
#pragma unroll
  for (int i = 0; i < 8; ++i) pv[i] = zf;

  // prologue: stage first K image (32KB = 8 x 16B per thread)
  {
    const uint* gsrc = P + (size_t)(jg * JPB) * PSTR;
#pragma unroll
    for (int it = 0; it < 8; ++it) {
      int idx = (it * NT + tid) << 2;
      gll16(gsrc + idx, sK + idx);
    }
  }

  for (int jj = 0; jj < JPB; ++jj) {
    const int jb = jg * JPB + jj;
    __syncthreads();  // B1: K image staged (vmcnt drained by barrier)

    // ---- QK^T, operand-swapped: A = K (from LDS), B = Q (resident) ----
    // C: col(l16) = Q-row (wv*16+l16), row(quad*4+reg) = K-row nt*16+quad*4+reg
    f32x4 ah[4], ar[4];
#pragma unroll
    for (int nt = 0; nt < 4; ++nt) { ah[nt] = zf; ar[nt] = zf; }
#pragma unroll
    for (int nt = 0; nt < 4; ++nt) {
      const int rB = nt * 16 + l16;      // K-row for the A-frag read
      const uint rowoff = (uint)rB * 64u;
      const uint swk = (uint)(rB & 15);
#pragma unroll
      for (int ks = 0; ks < 4; ++ks) {
        uint off = rowoff + ((((uint)(ks * 4 + quad)) ^ swk) << 2);
        f16x8 bh = *(const f16x8*)&sK[off];
        f16x8 br = *(const f16x8*)&sK[4096 + off];
        ah[nt] = MFMAH(bh, qh[ks], ah[nt]);
        ar[nt] = MFMAH(br, qh[ks], ar[nt]);
        ar[nt] = MFMAH(bh, qr[ks], ar[nt]);
      }
    }
    __syncthreads();  // B0: all waves done reading sK

    // ---- prefetch next K image (overlaps sort + PV below) ----
    if (jj + 1 < JPB) {
      const uint* gsrc = P + (size_t)(jb + 1) * PSTR;
#pragma unroll
      for (int it = 0; it < 8; ++it) {
        int idx = (it * NT + tid) << 2;
        gll16(gsrc + idx, sK + idx);
      }
    }

    // ---- top-p softmax, register-direct: this lane owns Q-row wv*16+l16;
    //      a[i] (i = nt*4+rg) is score at K-index nt*16 + q4 + rg ----
    {
      float a[16], e[16];
#pragma unroll
      for (int nt = 0; nt < 4; ++nt) {
        f32x4 s = ah[nt] + ar[nt];
#pragma unroll
        for (int rg = 0; rg < 4; ++rg) a[nt * 4 + rg] = s[rg];
      }
      // row max: local tree + cross-quad (lanes l16, l16+16, +32, +48)
      float mt[8];
#pragma unroll
      for (int i = 0; i < 8; ++i) mt[i] = fmaxf(a[i], a[i + 8]);
#pragma unroll
      for (int w2 = 4; w2 >= 1; w2 >>= 1)
#pragma unroll
        for (int i = 0; i < w2; ++i) mt[i] = fmaxf(mt[i], mt[i + w2]);
      float m = mt[0];
      m = fmaxf(m, __shfl_xor(m, 16, 64));
      m = fmaxf(m, __shfl_xor(m, 32, 64));
#pragma unroll
      for (int i = 0; i < 16; ++i) { a[i] = __expf(a[i] - m); e[i] = a[i]; }
      float st[8];
#pragma unroll
      for (int i = 0; i < 8; ++i) st[i] = a[i] + a[i + 8];
#pragma unroll
      for (int w2 = 4; w2 >= 1; w2 >>= 1)
#pragma unroll
        for (int i = 0; i < w2; ++i) st[i] += st[i + w2];
      float sr = st[0];
      sr += __shfl_xor(sr, 16, 64);
      sr += __shfl_xor(sr, 32, 64);
      const float T = THRESH * sr;

      // bitonic sort DESC over 64 = 4 quad-lanes x 16 regs (value-sort;
      // initial permutation irrelevant)
      const int s = quad;
#pragma unroll
      for (int k2 = 2; k2 <= 8; k2 <<= 1)
#pragma unroll
        for (int j2 = k2 >> 1; j2 >= 1; j2 >>= 1)
#pragma unroll
          for (int i = 0; i < 16; ++i) {
            int l = i ^ j2;
            if (l > i) { bool d = ((i & k2) == 0); CE(a[i], a[l], d); }
          }
      const bool x16 = ((s & 1) == 0);
      const bool x32 = ((s & 2) == 0);
#pragma unroll
      for (int j2 = 8; j2 >= 1; j2 >>= 1)
#pragma unroll
        for (int i = 0; i < 16; ++i) {
          int l = i ^ j2;
          if (l > i) { CE(a[i], a[l], x16); }
        }
      {
        const bool km = (x32 == x16);
#pragma unroll
        for (int i = 0; i < 16; ++i) {
          float o = __shfl_xor(a[i], 16, 64);
          a[i] = km ? fmaxf(a[i], o) : fminf(a[i], o);
        }
#pragma unroll
        for (int j2 = 8; j2 >= 1; j2 >>= 1)
#pragma unroll
          for (int i = 0; i < 16; ++i) {
            int l = i ^ j2;
            if (l > i) { CE(a[i], a[l], x32); }
          }
      }
      {
#pragma unroll
        for (int i = 0; i < 16; ++i) {
          float o = __shfl_xor(a[i], 32, 64);
          a[i] = x32 ? fmaxf(a[i], o) : fminf(a[i], o);
        }
#pragma unroll
        for (int i = 0; i < 16; ++i) {
          float o = __shfl_xor(a[i], 16, 64);
          a[i] = x16 ? fmaxf(a[i], o) : fminf(a[i], o);
        }
#pragma unroll
        for (int j2 = 8; j2 >= 1; j2 >>= 1)
#pragma unroll
          for (int i = 0; i < 16; ++i) {
            int l = i ^ j2;
            if (l > i) { CE(a[i], a[l], true); }
          }
      }
      // global inclusive cumsum, count t
#pragma unroll
      for (int i = 1; i < 16; ++i) a[i] += a[i - 1];
      float tot = a[15];
      float c = tot;
      float o1 = __shfl_up(c, 16, 64); if (s >= 1) c += o1;
      float o2 = __shfl_up(c, 32, 64); if (s >= 2) c += o2;
      const float excl = c - tot;
      int cnt = 0;
#pragma unroll
      for (int i = 0; i < 16; ++i) cnt += ((a[i] + excl) < T) ? 1 : 0;
      cnt += __shfl_xor(cnt, 16, 64);
      cnt += __shfl_xor(cnt, 32, 64);
      const int t = cnt;
      // renormalize first-t (ORIGINAL K order; kidx = nt*16 + q4 + rg)
      float p = 0.f;
#pragma unroll
      for (int i = 0; i < 16; ++i) {
        int kidx = ((i >> 2) << 4) + q4 + (i & 3);
        p += (kidx < t) ? e[i] : 0.f;
      }
      p += __shfl_xor(p, 16, 64);
      p += __shfl_xor(p, 32, 64);
      const float rn = 1.0f / (p + EPSF);
      // emit f16 weights: row l16, 16 chunks of 4 f16; chunk c4 = nt*4+quad
      // at swizzled uint offset row*32 + ((c4 ^ row) << 1)
      uint* wrow = sWw + l16 * 32;
#pragma unroll
      for (int nt = 0; nt < 4; ++nt) {
        UH4 u;
#pragma unroll
        for (int rg = 0; rg < 4; ++rg) {
          int kidx = nt * 16 + q4 + rg;
          float w = (kidx < t) ? e[nt * 4 + rg] * rn : 0.f;
          u.h[rg] = (_Float16)w;
        }
        uint c4 = (uint)(nt * 4 + quad);
        *(uint2*)&wrow[(c4 ^ (uint)l16) << 1] = u.u;
      }
    }
    __builtin_amdgcn_wave_barrier();  // weight writes before A-frag reads

    // ---- PV: A = f16 weights (wave-private LDS), B = Vt-frag from global ----
    f16x8 wf[2];
#pragma unroll
    for (int ks2 = 0; ks2 < 2; ++ks2) {
      uint c0 = (uint)(ks2 * 8 + quad * 2);
      const uint* wrow = sWw + l16 * 32;
      uint2 lo = *(const uint2*)&wrow[(c0 ^ (uint)l16) << 1];
      uint2 hi = *(const uint2*)&wrow[((c0 + 1) ^ (uint)l16) << 1];
      UH8 u;
      u.u = make_uint4(lo.x, lo.y, hi.x, hi.y);
      wf[ks2] = u.v;
    }
    {
      const uint* gvt = P + (size_t)jb * PSTR + 8192;
#pragma unroll
      for (int nt2 = 0; nt2 < 8; ++nt2) {
#pragma unroll
        for (int ks2 = 0; ks2 < 2; ++ks2) {
          f16x8 vf = *(const f16x8*)&gvt[((uint)((ks2 * 4 + quad) * 128 +
                                                 nt2 * 16 + l16)) << 2];
          pv[nt2] = MFMAH(wf[ks2], vf, pv[nt2]);
        }
      }
    }
  }

  // ---- epilogue: C-layout -> global atomicAdd over the 16 j-groups ----
#pragma unroll
  for (int nt2 = 0; nt2 < 8; ++nt2) {
    const int col  = nt2 * 16 + l16;
    const int row0 = ib * BLK + wv * 16 + quad * 4;
#pragma unroll
    for (int rg = 0; rg < 4; ++rg)
      atomicAdd(O + (size_t)(row0 + rg) * DIM + col, pv[nt2][rg]);
  }
}

extern "C" void kernel_launch(void* const* d_in, const int* in_sizes, int n_in,
                              void* d_out, int out_size, void* d_ws, size_t ws_size,
                              hipStream_t stream) {
  (void)in_sizes; (void)n_in; (void)ws_size; (void)out_size;
  const float* q = (const float*)d_in[0];
  const float* k = (const float*)d_in[1];
  const float* v = (const float*)d_in[2];
  float* out = (float*)d_out;
  uint* prep = (uint*)d_ws;   // 64 blocks x 48 KB = 3 MB

  eco_prep_kernel<<<dim3(NB * 4), dim3(NT), 0, stream>>>(k, v, prep, out);
  eco_attn_kernel<<<dim3(NJG, NB), dim3(NT), 0, stream>>>(q, prep, out);
}